// Round 10
// baseline (647.266 us; speedup 1.0000x reference)
//
#include <hip/hip_runtime.h>
#include <hip/hip_bf16.h>
#include <stdint.h>

typedef unsigned short u16;
typedef __bf16 bf16x8 __attribute__((ext_vector_type(8)));
typedef float floatx4 __attribute__((ext_vector_type(4)));

__device__ __forceinline__ u16 f2bf(float f) {
  union { float f; unsigned u; } c; c.f = f;
  unsigned r = c.u + 0x7fffu + ((c.u >> 16) & 1u);
  return (u16)(r >> 16);
}

__device__ __forceinline__ void load_lds16(const void* g, void* l) {
  __builtin_amdgcn_global_load_lds(
      (const __attribute__((address_space(1))) void*)g,
      (__attribute__((address_space(3))) void*)l,
      16, 0, 0);
}

__device__ __forceinline__ void memclob() { asm volatile("" ::: "memory"); }
__device__ __forceinline__ void barrier_() {
  memclob();
  __builtin_amdgcn_s_barrier();
  memclob();
}

// ---- preamble: cast x -> bf16 | transpose W0 | transpose W1 | zero z ----
__global__ __launch_bounds__(256) void preamble(
    const float* __restrict__ x, const float* __restrict__ W0,
    const float* __restrict__ W1,
    u16* __restrict__ Xb, u16* __restrict__ Wt0, u16* __restrict__ Wt1,
    float* __restrict__ z)
{
  __shared__ float tile[32][33];
  const int bid = blockIdx.x;
  const int t = threadIdx.x;

  if (bid < 32768) {                      // cast x: 32768*1024 floats, float4/thread
    int i = bid * 256 + t;
    float4 f = ((const float4*)x)[i];
    ushort4 u;
    u.x = f2bf(f.x); u.y = f2bf(f.y); u.z = f2bf(f.z); u.w = f2bf(f.w);
    ((ushort4*)Xb)[i] = u;
  } else if (bid < 32768 + 2048) {        // transpose W0 [1024,2048] -> [2048,1024]
    int tb = bid - 32768;
    int bx = (tb & 63) * 32, by = (tb >> 6) * 32;
    int tx = t & 31, ty = t >> 5;
    #pragma unroll
    for (int i = 0; i < 32; i += 8)
      tile[ty + i][tx] = W0[(size_t)(by + ty + i) * 2048 + bx + tx];
    __syncthreads();
    #pragma unroll
    for (int i = 0; i < 32; i += 8)
      Wt0[(size_t)(bx + ty + i) * 1024 + by + tx] = f2bf(tile[tx][ty + i]);
  } else if (bid < 32768 + 2048 + 4096) { // transpose W1 [2048,2048]
    int tb = bid - (32768 + 2048);
    int bx = (tb & 63) * 32, by = (tb >> 6) * 32;
    int tx = t & 31, ty = t >> 5;
    #pragma unroll
    for (int i = 0; i < 32; i += 8)
      tile[ty + i][tx] = W1[(size_t)(by + ty + i) * 2048 + bx + tx];
    __syncthreads();
    #pragma unroll
    for (int i = 0; i < 32; i += 8)
      Wt1[(size_t)(bx + ty + i) * 2048 + by + tx] = f2bf(tile[tx][ty + i]);
  } else {                                // zero z[32768]
    int tb = bid - (32768 + 2048 + 4096);
    ((float4*)z)[tb * 256 + t] = (float4){0.f, 0.f, 0.f, 0.f};
  }
}

// ========== 128x256 GEMM, BK=32, 2 blocks/CU: overlap from TLP ==========
// R9/R10.  R1-R8 lesson: the 256x256 1-block/CU structure is plateaued at
// 46-47% MfmaUtil -- the LDS read stream (~2300cyc/tile) and MFMA stream
// (2483) are serialized by barrier lockstep, and with only 2 waves/SIMD
// nothing fills the read windows.  Explicit phase-ahead pipelining spills
// (>80 live frag VGPR = scratch, R6/R7).  This kernel restores the m97/m114
// mechanism: CO-RESIDENT BLOCK diversity.  128x256 tile, BK=32, 8 waves of
// 64x64, LDS 2x24KB = 48KB, VGPR target <=128 (__launch_bounds__(512,4)) ->
// 2 blocks/CU = 4 waves/SIMD: block A's reads overlap block B's MFMAs with
// no scheduling heroics and no register pressure.
//
// Per K-tile (parity p): {barrier | stage(g+1)->lds[p^1] (3 gload_lds) |
// 8 ds_read_b128 from lds[p] | 16 independent MFMA | vmcnt(0)}.
//   WAR: stage(g+1) hits lds[p^1], whose readers (tile g-1) completed their
//   reads before their own MFMAs, hence before barrier(g).  OK.
//   RAW: reads(g) need stage(g): vmcnt(0) at end of tile g-1 drains it
//   (issued a full tile earlier), barrier(g) makes it global.  OK.
// Swizzle (BK=32, 64B rows): stored chunk = logical ^ ((row>>1)&3).  A wave's
// 64 read lanes (q 0..3 x rows lm 0..15) then cover 16 rows x 64B = 1KB
// bijectively -> conflict-free.  Staging source pre-swizzled: thread t row
// t>>2, physical chunk t&3, logical (t&3)^((t>>3)&3); LDS dest linear t*16B
// (both-sides rule, guide #21).  k-sequence per output element unchanged
// from R8 -> identical rounding/absmax.
// Canaries: OccupancyPercent ~45-50% (2 blocks resident; ~25% = VGPR fail),
// VGPR_Count <=128, WRITE_SIZE ~16.4MB (spill), SQ_LDS_BANK_CONFLICT 0.
template<bool FUSE_HEAD, int KK>
__global__ __launch_bounds__(512, 4) void gemm128x256(
    const u16* __restrict__ A,      // [M, KK] bf16
    const u16* __restrict__ Bt,     // [N, KK] bf16
    const float* __restrict__ bias, // [N]
    u16* __restrict__ C,            // [M, N] bf16 (unused if FUSE_HEAD)
    const float* __restrict__ W2,   // [N] (used if FUSE_HEAD)
    float* __restrict__ z,          // [M] fp32 accum (used if FUSE_HEAD)
    int M, int N)
{
  __shared__ u16 lds[2][12288];  // [p][ A:0..4095 = 128x32 | B:4096..12287 = 256x32 ]

  const int t = threadIdx.x;
  const int l = t & 63;
  const int w = t >> 6;        // 0..7
  const int wm = w >> 2;       // 0..1: M half (64 rows)
  const int wn = w & 3;        // 0..3: N quarter (64 cols)
  const int lm = l & 15;
  const int q  = l >> 4;       // 0..3

  // XCD-chunked bijective swizzle; grid = (N/256)*(M/128) = 2048, %8 == 0.
  // Blocks sharing an A-panel (consecutive wg) land on one XCD's L2.
  const int nwg = gridDim.x;
  int wg = blockIdx.x;
  wg = (wg & 7) * (nwg >> 3) + (wg >> 3);
  const int nbn = N >> 8;          // 8
  const int n0 = (wg % nbn) << 8;
  const int m0 = (wg / nbn) << 7;

  // ---- staging: 3 x gload_lds/thread = 24KB (A 8KB + B 16KB).
  // thread t -> row t>>2 (0..127), physical chunk t&3,
  // logical chunk (t&3)^((t>>3)&3)  [= (t&3)^((row>>1)&3)].
  const int srow = t >> 2;
  const int lc8 = ((t & 3) ^ ((t >> 3) & 3)) * 8;  // u16 units
  const u16* rA = A  + (size_t)(m0 + srow) * KK + lc8;
  const u16* rB = Bt + (size_t)(n0 + srow) * KK + lc8;
  const int ldst = t * 8;

#define STG(P, KOFF) do {                                                      \
    load_lds16(rA + (KOFF), &lds[P][ldst]);                                    \
    load_lds16(rB + (KOFF), &lds[P][4096 + ldst]);                             \
    load_lds16(rB + 128 * KK + (KOFF), &lds[P][8192 + ldst]);                  \
  } while (0)

  // ---- read geometry: row = (wm|wn)*64 + i*16 + lm; (row>>1)&3 == (lm>>1)&3
  // (i*16, wm*64 are multiples of 8) -> ck uniform across i/j.
  const int ck = (q ^ ((lm >> 1) & 3)) * 8;        // swizzled chunk, u16 units
  const int arow = (wm * 64 + lm) * 32;            // + i*512
  const int brow = 4096 + (wn * 64 + lm) * 32;     // + j*512
#define RDA(p, i) (*(const bf16x8*)&lds[p][arow + (i) * 512 + ck])
#define RDB(p, j) (*(const bf16x8*)&lds[p][brow + (j) * 512 + ck])
#define MFMA(d, x, y) d = __builtin_amdgcn_mfma_f32_16x16x32_bf16(x, y, d, 0, 0, 0)

  floatx4 acc[4][4];
  #pragma unroll
  for (int i = 0; i < 4; ++i)
    #pragma unroll
    for (int j = 0; j < 4; ++j)
      acc[i][j] = (floatx4){0.f, 0.f, 0.f, 0.f};

  constexpr int NK = KK >> 5;   // BK = 32
  static_assert(NK >= 4 && (NK & 1) == 0, "NK must be even, >= 4");

#define VMW0 asm volatile("s_waitcnt vmcnt(0)" ::: "memory")

  // One K-tile.  DOSTG/KOFF compile-time within the unrolled pair.
#define TILE(P, DOSTG, KOFF, DOVMW)                                            \
  {                                                                            \
    barrier_();                                                                \
    if (DOSTG) { STG((P) ^ 1, KOFF); }                                         \
    bf16x8 a_[4], b_[4];                                                       \
    _Pragma("unroll")                                                          \
    for (int i = 0; i < 4; ++i) a_[i] = RDA(P, i);                             \
    _Pragma("unroll")                                                          \
    for (int j = 0; j < 4; ++j) b_[j] = RDB(P, j);                             \
    __builtin_amdgcn_s_setprio(1);                                             \
    _Pragma("unroll")                                                          \
    for (int i = 0; i < 4; ++i)                                                \
      _Pragma("unroll")                                                        \
      for (int j = 0; j < 4; ++j)                                              \
        MFMA(acc[i][j], a_[i], b_[j]);                                         \
    __builtin_amdgcn_s_setprio(0);                                             \
    if (DOVMW) { VMW0; }                                                       \
  }

  // ---- prologue: stage tile 0, drain own 3 loads; barrier at loop top
  // makes all waves' slices globally visible.
  STG(0, 0);
  VMW0;

  // ---- steady state: 2 tiles/iter; pointers advance 64 u16 (2 tiles).
  // tile g (p=0): stage g+1 @+32 ; tile g+1 (p=1): stage g+2 @+64.
  #pragma unroll 1
  for (int g = 0; g < NK - 2; g += 2) {
    TILE(0, true, 32, true);
    TILE(1, true, 64, true);
    rA += 64; rB += 64;
  }
  // tail: tile NK-2 stages NK-1; tile NK-1 pure compute.
  TILE(0, true, 32, true);
  TILE(1, false, 0, false);

  // ---------------------------- epilogue ----------------------------
  float bv[4];
  #pragma unroll
  for (int j = 0; j < 4; ++j) bv[j] = bias[n0 + wn * 64 + j * 16 + lm];

  if (!FUSE_HEAD) {
    #pragma unroll
    for (int i = 0; i < 4; ++i) {
      #pragma unroll
      for (int r = 0; r < 4; ++r) {
        int grow = m0 + wm * 64 + i * 16 + q * 4 + r;
        size_t base = (size_t)grow * N + n0 + wn * 64 + lm;
        #pragma unroll
        for (int j = 0; j < 4; ++j) {
          float v = acc[i][j][r] + bv[j];
          v = v > 0.f ? v : (__expf(v) - 1.f);
          C[base + j * 16] = f2bf(v);
        }
      }
    }
  } else {
    float w2v[4];
    #pragma unroll
    for (int j = 0; j < 4; ++j) w2v[j] = W2[n0 + wn * 64 + j * 16 + lm];
    #pragma unroll
    for (int i = 0; i < 4; ++i) {
      #pragma unroll
      for (int r = 0; r < 4; ++r) {
        float pacc = 0.f;
        #pragma unroll
        for (int j = 0; j < 4; ++j) {
          float v = acc[i][j][r] + bv[j];
          v = v > 0.f ? v : (__expf(v) - 1.f);
          pacc += v * w2v[j];
        }
        pacc += __shfl_xor(pacc, 1);
        pacc += __shfl_xor(pacc, 2);
        pacc += __shfl_xor(pacc, 4);
        pacc += __shfl_xor(pacc, 8);
        if (lm == 0) atomicAdd(&z[m0 + wm * 64 + i * 16 + q * 4 + r], pacc);
      }
    }
  }
#undef STG
#undef RDA
#undef RDB
#undef MFMA
#undef TILE
#undef VMW0
}

// ------------- finish: out = sigmoid(z + b2); alpha = acti(out) -------------
__global__ __launch_bounds__(256) void sigmoid_alpha(
    const float* __restrict__ z, const float* __restrict__ b2,
    float* __restrict__ out, int B)
{
  int i = blockIdx.x * blockDim.x + threadIdx.x;
  if (i >= B) return;
  float o = 1.f / (1.f + expf(-(z[i] + b2[0])));
  float alpha;
  if (o <= 0.2f)      alpha = 0.1f - 0.5f * o;
  else if (o >= 0.8f) alpha = 0.5f * o - 0.4f;
  else                alpha = 0.f;
  out[i] = o;
  out[B + i] = alpha;
}

extern "C" void kernel_launch(void* const* d_in, const int* in_sizes, int n_in,
                              void* d_out, int out_size, void* d_ws, size_t ws_size,
                              hipStream_t stream) {
  const int BATCH = 32768, HID = 2048;

  const float* x  = (const float*)d_in[0];
  const float* W0 = (const float*)d_in[1];
  const float* b0 = (const float*)d_in[2];
  const float* W1 = (const float*)d_in[3];
  const float* b1 = (const float*)d_in[4];
  const float* W2 = (const float*)d_in[5];
  const float* b2 = (const float*)d_in[6];
  float* out = (float*)d_out;

  char* ws = (char*)d_ws;
  u16* Xb   = (u16*)(ws);                       // 64 MB [32768,1024]
  u16* Wt0  = (u16*)(ws + (size_t)67108864);    // 4 MB  [2048,1024]
  u16* Wt1  = (u16*)(ws + (size_t)71303168);    // 8 MB  [2048,2048]
  u16* h0   = (u16*)(ws + (size_t)79691776);    // 128 MB [32768,2048]
  float* z  = (float*)(ws + (size_t)213909504); // 128 KB [32768]

  const int grid = (HID / 256) * (BATCH / 128); // 2048, divisible by 8

  // 1) preamble: cast x, transpose W0/W1, zero z
  preamble<<<32768 + 2048 + 4096 + 32, 256, 0, stream>>>(x, W0, W1, Xb, Wt0, Wt1, z);
  // 2) h0 = elu(Xb @ Wt0^T + b0)
  gemm128x256<false, 1024><<<grid, 512, 0, stream>>>(
      Xb, Wt0, b0, h0, nullptr, nullptr, BATCH, HID);
  // 3) z += rows of elu(h0 @ Wt1^T + b1) dotted with W2 (h1 never stored)
  gemm128x256<true, 2048><<<grid, 512, 0, stream>>>(
      h0, Wt1, b1, nullptr, W2, z, BATCH, HID);
  // 4) out + alpha
  sigmoid_alpha<<<BATCH / 256, 256, 0, stream>>>(z, b2, out, BATCH);
}